// Round 1
// baseline (472.830 us; speedup 1.0000x reference)
//
#include <hip/hip_runtime.h>

// ---------------------------------------------------------------------------
// SelfInteraction: 2 layers of (tensor-square -> invariant-gated MLP -> equiv
// linear) + residual + eq-layernorm, N=16384 rows, C=128, all fp32 I/O.
// Strategy: fp16 hi/lo split-precision MFMA GEMMs (22-bit effective mantissa).
// A (activations) stored as [hi(0..K-1) | lo(K..2K-1)], B (weights) stored
// pre-split/pre-scaled as K''=3K segments [B_hi ; B_lo ; B_hi]; the GEMM
// k-loop pairs chunks (A_hi,B_hi),(A_hi,B_lo),(A_lo,B_hi) => compensated fp32.
// Internal v layout: (N, 3, C)  (d-major) so the einsum is a plain GEMM.
// ---------------------------------------------------------------------------

typedef _Float16 half8 __attribute__((ext_vector_type(8)));
typedef float floatx4 __attribute__((ext_vector_type(4)));

static inline int cdiv_h(int a, int b){ return (a + b - 1) / b; }

// ---------------------------- device helpers -------------------------------

__device__ __forceinline__ void stage16(const char* gaddr, char* lds_wave_base, int lane){
#if __has_builtin(__builtin_amdgcn_global_load_lds)
  // dest = wave-uniform base + lane*16 (measured semantics, learn_hip m104/m108)
  __builtin_amdgcn_global_load_lds((const __attribute__((address_space(1))) unsigned int*)gaddr,
                                   (__attribute__((address_space(3))) unsigned int*)lds_wave_base,
                                   16, 0, 0);
#else
  *(float4*)(lds_wave_base + lane*16) = *(const float4*)gaddr;
#endif
}

__device__ __forceinline__ float wave_sum64(float x){
  #pragma unroll
  for (int m = 32; m; m >>= 1) x += __shfl_xor(x, m, 64);
  return x;
}

// ---------------------------- weight prep ----------------------------------
// w row-major (K, ldw); writes BT' [col][3K]: seg0=hi, seg1=lo, seg2=hi (dup).
__global__ __launch_bounds__(256) void prep_w(const float* __restrict__ w,
                                              _Float16* __restrict__ o,
                                              int K, int ldw, int ncols, float scale){
  int idx = blockIdx.x*256 + threadIdx.x;
  if (idx >= K*ncols) return;
  int col = idx / K, k = idx - col*K;
  float v = w[(size_t)k*ldw + col] * scale;
  _Float16 hi = (_Float16)v;
  _Float16 lo = (_Float16)(v - (float)hi);
  size_t b = (size_t)col*3*K + k;
  o[b]       = hi;
  o[b + K]   = lo;
  o[b + 2*K] = hi;
}

// ---------------------------- E0: unpack x ---------------------------------
// x[n, 0:128] -> S ; x[n, 128 + c*3 + d] -> V[(n*3+d)*128 + c]
__global__ __launch_bounds__(256) void e0_load(const float* __restrict__ x,
                                               float* __restrict__ S, float* __restrict__ V,
                                               int R, int row0){
  int idx = blockIdx.x*256 + threadIdx.x;
  if (idx >= R*512) return;
  int n = idx >> 9, j = idx & 511;
  float val = x[(size_t)(row0 + n)*512 + j];
  if (j < 128) S[(size_t)n*128 + j] = val;
  else {
    int jj = j - 128;
    int ch = jj / 3;
    int d  = jj - ch*3;
    V[((size_t)n*3 + d)*128 + ch] = val;
  }
}

// ---------------------------- E1: build sc' --------------------------------
// sc = [s, s^2, |v|^2/sqrt(3)], split hi/lo into A1 (lda=768, lo at +384)
__global__ __launch_bounds__(256) void e1_sc(const float* __restrict__ S,
                                             const float* __restrict__ V,
                                             _Float16* __restrict__ A1, int R){
  int idx = blockIdx.x*256 + threadIdx.x;
  if (idx >= R*384) return;
  int n = idx / 384, c = idx - n*384;
  float val;
  if (c < 128) val = S[(size_t)n*128 + c];
  else if (c < 256){ float s = S[(size_t)n*128 + c - 128]; val = s*s; }
  else {
    int ch = c - 256;
    float a = V[((size_t)n*3 + 0)*128 + ch];
    float b = V[((size_t)n*3 + 1)*128 + ch];
    float d = V[((size_t)n*3 + 2)*128 + ch];
    val = (a*a + b*b + d*d) * 0.5773502691896258f;  // 1/sqrt(3)
  }
  _Float16 hi = (_Float16)val;
  _Float16 lo = (_Float16)(val - (float)hi);
  A1[(size_t)n*768 + c]       = hi;
  A1[(size_t)n*768 + 384 + c] = lo;
}

// ---------------------------- E2: gating -----------------------------------
// m<384 : A1 <- (sc * g_s) in place (sc reconstructed exactly as hi+lo)
// m>=384: A4[(n*3+d)*512 + mm] <- vec[n,mm,d] * g_v   (vec = v or sqrt2*s*v)
__global__ __launch_bounds__(256) void e2_gate(const float* __restrict__ S,
                                               const float* __restrict__ V,
                                               const float* __restrict__ G,
                                               _Float16* __restrict__ A1,
                                               _Float16* __restrict__ A4, int R){
  int idx = blockIdx.x*256 + threadIdx.x;
  if (idx >= R*640) return;
  int n = idx / 640, m = idx - n*640;
  if (m < 384){
    float sc = (float)A1[(size_t)n*768 + m] + (float)A1[(size_t)n*768 + 384 + m];
    float val = sc * G[(size_t)n*640 + m];
    _Float16 hi = (_Float16)val;
    _Float16 lo = (_Float16)(val - (float)hi);
    A1[(size_t)n*768 + m]       = hi;
    A1[(size_t)n*768 + 384 + m] = lo;
  } else {
    int mm = m - 384;                    // 0..255
    float gv = G[(size_t)n*640 + m];
    int ch = mm & 127;
    float smul = (mm >= 128) ? 1.4142135623730951f * S[(size_t)n*128 + ch] : 1.0f;
    #pragma unroll
    for (int d = 0; d < 3; ++d){
      float val = V[((size_t)n*3 + d)*128 + ch] * smul * gv;
      _Float16 hi = (_Float16)val;
      _Float16 lo = (_Float16)(val - (float)hi);
      size_t b = ((size_t)n*3 + d)*512 + mm;
      A4[b]       = hi;
      A4[b + 256] = lo;
    }
  }
}

// ---------------------------- E3: residual + LN / final --------------------
// one 64-lane wave per row; doln=1: eq_layernorm back into state;
// doln=0: write final output (s | v interleaved (C,3)).
__global__ __launch_bounds__(256) void e3_fin(float* __restrict__ S, float* __restrict__ V,
                                              const float* __restrict__ OS, const float* __restrict__ OV,
                                              const float* __restrict__ g0, const float* __restrict__ g1,
                                              float* __restrict__ out, int R, int row0, int doln){
  int n = blockIdx.x*4 + (threadIdx.x >> 6);
  int lane = threadIdx.x & 63;
  size_t sb = (size_t)n*128;
  size_t vb = (size_t)n*384;
  float s0 = S[sb + lane]      + OS[sb + lane];
  float s1 = S[sb + 64 + lane] + OS[sb + 64 + lane];
  float v[6];
  #pragma unroll
  for (int k = 0; k < 6; ++k) v[k] = V[vb + k*64 + lane] + OV[vb + k*64 + lane];

  if (doln){
    float mu = wave_sum64(s0 + s1) * (1.0f/128.0f);
    float d0 = s0 - mu, d1 = s1 - mu;
    float var = wave_sum64(d0*d0 + d1*d1) * (1.0f/128.0f);
    float sd = sqrtf(var + 1e-6f);
    float vv = 0.f;
    #pragma unroll
    for (int k = 0; k < 6; ++k) vv += v[k]*v[k];
    float rms = sqrtf(wave_sum64(vv) * (1.0f/384.0f) + 1e-6f);
    S[sb + lane]      = d0 / sd * g0[lane];
    S[sb + 64 + lane] = d1 / sd * g0[64 + lane];
    #pragma unroll
    for (int k = 0; k < 6; ++k){
      int j = k*64 + lane;
      V[vb + j] = v[k] / rms * g1[j & 127];
    }
  } else {
    size_t ob = (size_t)(row0 + n)*512;
    out[ob + lane]      = s0;
    out[ob + 64 + lane] = s1;
    #pragma unroll
    for (int k = 0; k < 6; ++k){
      int j = k*64 + lane;
      int d = j >> 7, ch = j & 127;
      out[ob + 128 + ch*3 + d] = v[k];
    }
  }
}

// ---------------------------- split-GEMM -----------------------------------
// C[M x ncols] = A[M x 2*kbase (hi|lo)] x BT[ncols x 3*kbase]^T
// 128x128 tile, 4 waves (each 64x64 = 4x4 MFMA tiles), 16x16x32 f16 MFMA,
// double-buffered LDS staged with global_load_lds width-16.
// MODE 0: plain f32 store to C (ldc). MODE 1: silu + hi/lo split into SP
// (lda 768, lo at col+384) -- GEMM1's h-operand for GEMM2.
template<int MODE>
__global__ __launch_bounds__(256) void gemm_split(const _Float16* __restrict__ A,
                                                  const _Float16* __restrict__ BT,
                                                  float* __restrict__ C,
                                                  _Float16* __restrict__ SP,
                                                  int lda, int kbase, int ldc){
  __shared__ alignas(16) _Float16 lA[2][4096];   // 128 rows x 32 halves
  __shared__ alignas(16) _Float16 lB[2][4096];
  const int nsc  = kbase >> 5;       // chunks per segment
  const int nch  = 3*nsc;
  const int ldbt = 3*kbase;
  const int tid  = threadIdx.x;
  const int wave = tid >> 6, lane = tid & 63;
  const int m0 = blockIdx.x << 7, c0 = blockIdx.y << 7;
  const int wm = wave & 1, wn = wave >> 1;
  const int r = lane & 15, kg = lane >> 4;

  floatx4 acc[4][4];
  #pragma unroll
  for (int i = 0; i < 4; ++i)
    #pragma unroll
    for (int j = 0; j < 4; ++j) acc[i][j] = (floatx4){0.f, 0.f, 0.f, 0.f};

  auto stage = [&](int c, int buf){
    const int ka = ((c < nsc) ? c : c - nsc) << 5;   // A seg map: hi,hi,lo
    const int kb = c << 5;
    #pragma unroll
    for (int p = 0; p < 2; ++p){
      const int lbase = wave*1024 + p*4096;          // wave-uniform byte base
      const int off = lbase + lane*16;
      const int row = off >> 6, bir = off & 63;
      const char* ga = (const char*)A  + (((size_t)(m0 + row))*lda  + ka)*2 + bir;
      stage16(ga, (char*)(&lA[buf][0]) + lbase, lane);
      const char* gb = (const char*)BT + (((size_t)(c0 + row))*ldbt + kb)*2 + bir;
      stage16(gb, (char*)(&lB[buf][0]) + lbase, lane);
    }
  };

  stage(0, 0);
  for (int c = 0; c < nch; ++c){
    __syncthreads();                      // drains vmcnt -> buf[c&1] ready
    if (c + 1 < nch) stage(c + 1, (c + 1) & 1);
    const _Float16* a_ = &lA[c & 1][0];
    const _Float16* b_ = &lB[c & 1][0];
    half8 af[4], bf[4];
    #pragma unroll
    for (int mt = 0; mt < 4; ++mt)
      af[mt] = *(const half8*)(a_ + ((wm*64 + mt*16 + r)*32 + kg*8));
    #pragma unroll
    for (int nt = 0; nt < 4; ++nt)
      bf[nt] = *(const half8*)(b_ + ((wn*64 + nt*16 + r)*32 + kg*8));
    #pragma unroll
    for (int mt = 0; mt < 4; ++mt)
      #pragma unroll
      for (int nt = 0; nt < 4; ++nt)
        acc[mt][nt] = __builtin_amdgcn_mfma_f32_16x16x32_f16(af[mt], bf[nt], acc[mt][nt], 0, 0, 0);
  }

  #pragma unroll
  for (int mt = 0; mt < 4; ++mt){
    #pragma unroll
    for (int nt = 0; nt < 4; ++nt){
      #pragma unroll
      for (int i = 0; i < 4; ++i){
        const int row = m0 + wm*64 + mt*16 + kg*4 + i;   // C/D: row = quad*4+i
        const int col = c0 + wn*64 + nt*16 + r;          //      col = lane&15
        float v = acc[mt][nt][i];
        if (MODE == 0){
          C[(size_t)row*ldc + col] = v;
        } else {
          float h = v / (1.0f + __expf(-v));             // silu
          _Float16 hi = (_Float16)h;
          _Float16 lo = (_Float16)(h - (float)hi);
          SP[(size_t)row*768 + col]       = hi;
          SP[(size_t)row*768 + 384 + col] = lo;
        }
      }
    }
  }
}

// ---------------------------- host launcher --------------------------------

extern "C" void kernel_launch(void* const* d_in, const int* in_sizes, int n_in,
                              void* d_out, int out_size, void* d_ws, size_t ws_size,
                              hipStream_t stream){
  const float* x  = (const float*)d_in[0];
  const float* w1 = (const float*)d_in[1];
  const float* w2 = (const float*)d_in[2];
  const float* w0 = (const float*)d_in[3];
  const float* wv = (const float*)d_in[4];
  const float* g0 = (const float*)d_in[5];
  const float* g1 = (const float*)d_in[6];
  float* out = (float*)d_out;
  const int N = in_sizes[0] / 512;                 // 16384
  const float RS384 = 0.051031036307982884f;       // 1/sqrt(384)

  // split-weight arena: per layer 1,425,408 halves
  const size_t HL = 1425408;
  _Float16* W = (_Float16*)d_ws;
  const size_t wbytes = 2*HL*2;                    // 5,701,632 B

  // pick N-chunking that fits ws (activations cost 12800 B/row)
  int cnum = 128;
  for (int cc = 1; cc <= 128; cc <<= 1){
    size_t need = wbytes + (size_t)(N/cc)*12800;
    if (need <= ws_size){ cnum = cc; break; }
  }
  const int R = N / cnum;                          // multiple of 128

  char* p = (char*)d_ws + wbytes;
  float*    Sst = (float*)p;     p += (size_t)R*512;
  float*    Vst = (float*)p;     p += (size_t)R*1536;
  _Float16* A1  = (_Float16*)p;  p += (size_t)R*1536;   // sc' then gated sc'
  _Float16* A2  = (_Float16*)p;  p += (size_t)R*1536;   // h'
  float*    G   = (float*)p;     p += (size_t)R*2560;   // g (N x 640)
  _Float16* A4  = (_Float16*)p;  p += (size_t)R*3072;   // gated vec' (3R x 512)
  float*    OS  = (float*)p;     p += (size_t)R*512;
  float*    OV  = (float*)p;     p += (size_t)R*1536;

  // weight prep (runs every call; ws is re-poisoned before each timed launch)
  for (int l = 0; l < 2; ++l){
    _Float16* W1p = W + (size_t)l*HL;
    _Float16* W2p = W1p + 442368;
    _Float16* W0p = W1p + 1179648;
    _Float16* WVp = W1p + 1327104;
    prep_w<<<cdiv_h(384*384,256),256,0,stream>>>(w1 + (size_t)l*384*384, W1p, 384, 384, 384, RS384);
    prep_w<<<cdiv_h(384*640,256),256,0,stream>>>(w2 + (size_t)l*384*768, W2p, 384, 768, 640, RS384);
    prep_w<<<cdiv_h(384*128,256),256,0,stream>>>(w0 + (size_t)l*384*128, W0p, 384, 128, 128, RS384);
    prep_w<<<cdiv_h(256*128,256),256,0,stream>>>(wv + (size_t)l*256*128, WVp, 256, 128, 128, 0.0625f);
  }

  for (int chk = 0; chk < cnum; ++chk){
    const int row0 = chk*R;
    e0_load<<<cdiv_h(R*512,256),256,0,stream>>>(x, Sst, Vst, R, row0);
    for (int l = 0; l < 2; ++l){
      _Float16* W1p = W + (size_t)l*HL;
      _Float16* W2p = W1p + 442368;
      _Float16* W0p = W1p + 1179648;
      _Float16* WVp = W1p + 1327104;
      e1_sc<<<cdiv_h(R*384,256),256,0,stream>>>(Sst, Vst, A1, R);
      gemm_split<1><<<dim3(R/128,3),256,0,stream>>>(A1, W1p, nullptr, A2, 768, 384, 0);
      gemm_split<0><<<dim3(R/128,5),256,0,stream>>>(A2, W2p, G, nullptr, 768, 384, 640);
      e2_gate<<<cdiv_h(R*640,256),256,0,stream>>>(Sst, Vst, G, A1, A4, R);
      gemm_split<0><<<dim3(R/128,1),256,0,stream>>>(A1, W0p, OS, nullptr, 768, 384, 128);
      gemm_split<0><<<dim3(3*R/128,1),256,0,stream>>>(A4, WVp, OV, nullptr, 512, 256, 128);
      e3_fin<<<R/4,256,0,stream>>>(Sst, Vst, OS, OV, g0, g1, out, R, row0, (l == 0) ? 1 : 0);
    }
  }
}